// Round 7
// baseline (619.574 us; speedup 1.0000x reference)
//
#include <hip/hip_runtime.h>
#include <math.h>

#define NEGV (-1000.0f)
#define SLOPE 0.01f
#define D_IN 256
#define LDK 72

typedef _Float16 half8 __attribute__((ext_vector_type(8)));
typedef _Float16 half4h __attribute__((ext_vector_type(4)));
typedef float f32x4 __attribute__((ext_vector_type(4)));

// ---------- W prep: W[h][k][f] fp32 -> split fp16 Wt_hi/Wt_lo[c][k], c=f*4+h ----------
__global__ void wprep_kernel(const float* __restrict__ W, _Float16* __restrict__ Wt_hi,
                             _Float16* __restrict__ Wt_lo) {
    int i = blockIdx.x * 256 + threadIdx.x;   // 65536, input-coalesced
    int f = i & 63;
    int k = (i >> 6) & 255;
    int h = i >> 14;
    float w = W[i];
    _Float16 hi = (_Float16)w;
    _Float16 lo = (_Float16)(w - (float)hi);
    int c = f * 4 + h;
    Wt_hi[c * 256 + k] = hi;
    Wt_lo[c * 256 + k] = lo;
}

// ---------- split-fp16 MFMA GEMM: z_t[n][c] = sum_k h[n][k]*Wt[c][k], fp32 out ----------
// (byte-identical to the proven r0 GEMM)
// BM=128, BN=128, BK=64; 512 thr = 8 waves; wave w: rows (w&3)*32 (2 tiles), cols (w>>2)*64 (4 tiles)
__global__ __launch_bounds__(512) void gemm_kernel(const float* __restrict__ hmat,
        const _Float16* __restrict__ Wt_hi, const _Float16* __restrict__ Wt_lo,
        float* __restrict__ z_t, int N) {
    __shared__ __align__(16) _Float16 smem[4 * 128 * LDK];   // 73728 B
    _Float16* A_hi = smem;
    _Float16* A_lo = smem + 128 * LDK;
    _Float16* B_hi = smem + 2 * 128 * LDK;
    _Float16* B_lo = smem + 3 * 128 * LDK;
    const int t = threadIdx.x;
    const int lane = t & 63;
    const int w = t >> 6;
    const int quad = lane >> 4;
    const int m16 = lane & 15;
    const int rg = w & 3;
    const int cg = w >> 2;
    const int n0 = (blockIdx.x >> 1) * 128;
    const int c0 = (blockIdx.x & 1) * 128;

    f32x4 acc[2][4];
#pragma unroll
    for (int rt = 0; rt < 2; rt++)
#pragma unroll
        for (int ct = 0; ct < 4; ct++) acc[rt][ct] = (f32x4){0.f, 0.f, 0.f, 0.f};

    for (int kc = 0; kc < 256; kc += 64) {
        __syncthreads();
        // stage A: 128 rows x 64 k, fp32 -> hi/lo fp16
#pragma unroll
        for (int i = 0; i < 4; i++) {
            int idx = i * 512 + t;                    // 0..2047
            int row = idx >> 4, q = idx & 15;
            int rr = min(n0 + row, N - 1);            // clamp; garbage rows masked at store
            float4 v = *(const float4*)&hmat[(size_t)rr * 256 + kc + q * 4];
            half4h hv, lv;
            hv[0] = (_Float16)v.x; lv[0] = (_Float16)(v.x - (float)hv[0]);
            hv[1] = (_Float16)v.y; lv[1] = (_Float16)(v.y - (float)hv[1]);
            hv[2] = (_Float16)v.z; lv[2] = (_Float16)(v.z - (float)hv[2]);
            hv[3] = (_Float16)v.w; lv[3] = (_Float16)(v.w - (float)hv[3]);
            *(half4h*)&A_hi[row * LDK + q * 4] = hv;
            *(half4h*)&A_lo[row * LDK + q * 4] = lv;
        }
        // stage B: 128 c x 64 k fp16 hi/lo
#pragma unroll
        for (int i = 0; i < 2; i++) {
            int idx = i * 512 + t;                    // 0..1023
            int c = idx >> 3, seg = idx & 7;
            float4 vh = *(const float4*)&Wt_hi[(c0 + c) * 256 + kc + seg * 8];
            float4 vl = *(const float4*)&Wt_lo[(c0 + c) * 256 + kc + seg * 8];
            *(float4*)&B_hi[c * LDK + seg * 8] = vh;
            *(float4*)&B_lo[c * LDK + seg * 8] = vl;
        }
        __syncthreads();
#pragma unroll
        for (int ks = 0; ks < 2; ks++) {
            half8 ah[2], al[2], bh[4], bl[4];
#pragma unroll
            for (int rt = 0; rt < 2; rt++) {
                int ro = ((rg * 2 + rt) * 16 + m16) * LDK + ks * 32 + quad * 8;
                ah[rt] = *(const half8*)&A_hi[ro];
                al[rt] = *(const half8*)&A_lo[ro];
            }
#pragma unroll
            for (int ct = 0; ct < 4; ct++) {
                int co = ((cg * 4 + ct) * 16 + m16) * LDK + ks * 32 + quad * 8;
                bh[ct] = *(const half8*)&B_hi[co];
                bl[ct] = *(const half8*)&B_lo[co];
            }
#pragma unroll
            for (int rt = 0; rt < 2; rt++)
#pragma unroll
                for (int ct = 0; ct < 4; ct++) {
                    acc[rt][ct] = __builtin_amdgcn_mfma_f32_16x16x32_f16(ah[rt], bh[ct], acc[rt][ct], 0, 0, 0);
                    acc[rt][ct] = __builtin_amdgcn_mfma_f32_16x16x32_f16(al[rt], bh[ct], acc[rt][ct], 0, 0, 0);
                    acc[rt][ct] = __builtin_amdgcn_mfma_f32_16x16x32_f16(ah[rt], bl[ct], acc[rt][ct], 0, 0, 0);
                }
        }
    }
    // epilogue: C/D col=lane&15, row=quad*4+reg; direct fp32 stores (16-lane coalesced)
#pragma unroll
    for (int rt = 0; rt < 2; rt++)
#pragma unroll
        for (int ct = 0; ct < 4; ct++)
#pragma unroll
            for (int r = 0; r < 4; r++) {
                int n = n0 + rg * 32 + rt * 16 + quad * 4 + r;
                int c = c0 + cg * 64 + ct * 16 + m16;
                if (n < N) z_t[(size_t)n * 256 + c] = acc[rt][ct][r];
            }
}

// ---------- es/ed per node (fp32 z) + in-row fp16 z image for the aggregation ----------
// Each z_t row is 1024 B of fp32. After the full row is loaded (one wave = one row),
// the fp16 image of the row (512 B) is written into bytes [512,1024) of the SAME row,
// overwriting fp32 halves already consumed. Single writer per byte; no cross-row hazard.
__global__ void esed_kernel(float* __restrict__ z_t, const float* __restrict__ att,
                            float* __restrict__ es_ed, int N) {
    int gid = blockIdx.x * blockDim.x + threadIdx.x;
    int n = gid >> 6;
    int lane = gid & 63;
    if (n >= N) return;
    float4 zv = *(const float4*)&z_t[(size_t)n * 256 + lane * 4];
    float ps0 = zv.x * att[0 * 128 + lane];
    float ps1 = zv.y * att[1 * 128 + lane];
    float ps2 = zv.z * att[2 * 128 + lane];
    float ps3 = zv.w * att[3 * 128 + lane];
    float pd0 = zv.x * att[0 * 128 + 64 + lane];
    float pd1 = zv.y * att[1 * 128 + 64 + lane];
    float pd2 = zv.z * att[2 * 128 + 64 + lane];
    float pd3 = zv.w * att[3 * 128 + 64 + lane];
    for (int off = 1; off < 64; off <<= 1) {
        ps0 += __shfl_xor(ps0, off); ps1 += __shfl_xor(ps1, off);
        ps2 += __shfl_xor(ps2, off); ps3 += __shfl_xor(ps3, off);
        pd0 += __shfl_xor(pd0, off); pd1 += __shfl_xor(pd1, off);
        pd2 += __shfl_xor(pd2, off); pd3 += __shfl_xor(pd3, off);
    }
    // fp16 image: half index n*512 + 256 + lane*4  (= byte n*1024 + 512 + lane*8)
    half4h h16;
    h16[0] = (_Float16)zv.x; h16[1] = (_Float16)zv.y;
    h16[2] = (_Float16)zv.z; h16[3] = (_Float16)zv.w;
    *(half4h*)((_Float16*)z_t + (size_t)n * 512 + 256 + lane * 4) = h16;
    if (lane == 0) {
        *(float4*)&es_ed[(size_t)n * 8]     = make_float4(ps0, ps1, ps2, ps3);
        *(float4*)&es_ed[(size_t)n * 8 + 4] = make_float4(pd0, pd1, pd2, pd3);
    }
}

// ---------- CSR build ----------
__global__ void hist_kernel(const int* __restrict__ dst, int* __restrict__ counts, int E) {
    int i = blockIdx.x * blockDim.x + threadIdx.x;
    if (i < E) atomicAdd(&counts[dst[i]], 1);
}

__global__ void scanA_kernel(const int* __restrict__ counts, int* __restrict__ bsums, int N) {
    __shared__ int lds[256];
    int t = threadIdx.x;
    int base = blockIdx.x * 1024 + t * 4;
    int s = 0;
    if (base + 3 < N) {
        int4 v = *(const int4*)&counts[base];
        s = v.x + v.y + v.z + v.w;
    } else {
        for (int u = 0; u < 4; u++) if (base + u < N) s += counts[base + u];
    }
    lds[t] = s; __syncthreads();
    for (int off = 128; off > 0; off >>= 1) {
        if (t < off) lds[t] += lds[t + off];
        __syncthreads();
    }
    if (t == 0) bsums[blockIdx.x] = lds[0];
}

__global__ void scanB_kernel(int* __restrict__ bsums, int nb) {
    __shared__ int lds[256];
    int t = threadIdx.x;
    int v = (t < nb) ? bsums[t] : 0;
    lds[t] = v; __syncthreads();
    for (int off = 1; off < 256; off <<= 1) {
        int x = (t >= off) ? lds[t - off] : 0;
        __syncthreads();
        lds[t] += x;
        __syncthreads();
    }
    if (t < nb) bsums[t] = lds[t] - v;   // exclusive
}

__global__ void scanC_kernel(const int* __restrict__ counts, const int* __restrict__ bsums,
                             int* __restrict__ row_start, int N) {
    __shared__ int lds[256];
    int t = threadIdx.x;
    int base = blockIdx.x * 1024 + t * 4;
    int4 v = make_int4(0, 0, 0, 0);
    if (base + 3 < N) v = *(const int4*)&counts[base];
    else {
        if (base + 0 < N) v.x = counts[base + 0];
        if (base + 1 < N) v.y = counts[base + 1];
        if (base + 2 < N) v.z = counts[base + 2];
    }
    int s = v.x + v.y + v.z + v.w;
    lds[t] = s; __syncthreads();
    for (int off = 1; off < 256; off <<= 1) {
        int x = (t >= off) ? lds[t - off] : 0;
        __syncthreads();
        lds[t] += x;
        __syncthreads();
    }
    int excl = lds[t] - s + bsums[blockIdx.x];
    int4 r;
    r.x = excl; r.y = r.x + v.x; r.z = r.y + v.y; r.w = r.z + v.z;
    if (base + 3 < N) *(int4*)&row_start[base] = r;
    else {
        if (base + 0 < N) row_start[base + 0] = r.x;
        if (base + 1 < N) row_start[base + 1] = r.y;
        if (base + 2 < N) row_start[base + 2] = r.z;
    }
}

__global__ void scatter_kernel(const int* __restrict__ src, const int* __restrict__ dst,
                               const int* __restrict__ row_start, int* __restrict__ cursor,
                               int* __restrict__ csr_src, int E) {
    int i = blockIdx.x * blockDim.x + threadIdx.x;
    if (i < E) {
        int d = dst[i];
        int pos = row_start[d] + atomicAdd(&cursor[d], 1);
        csr_src[pos] = src[i];
    }
}

// ---------- aggregation: one wave per node, online softmax, fp16 in-row z gathers ----------
// z16 = (const _Float16*)z_t; row n's fp16 image lives at half index n*512 + 256.
// Latency fix: z-row addresses depend only on s (known at tile start), so 16 prefetch
// loads are issued BEFORE the es-gather/softmax chain; the consumption loop (unchanged
// from the passing r6 kernel) then re-reads warm L1/L2 lines. Keep-alive asm prevents
// DCE of the prefetch loads; it sits after softmax so waits land where latency is hidden.
__global__ __launch_bounds__(256) void aggregate_kernel(const _Float16* __restrict__ z16,
        const float* __restrict__ es_ed, const int* __restrict__ csr_src,
        const int* __restrict__ row_start, const int* __restrict__ counts,
        float* __restrict__ out, int N) {
    int gid = blockIdx.x * blockDim.x + threadIdx.x;
    int n = gid >> 6;
    int lane = gid & 63;   // = f
    if (n >= N) return;
    int cnt = counts[n];
    int start = row_start[n];
    float4 edn = *(const float4*)&es_ed[(size_t)n * 8 + 4];

    float m0 = -INFINITY, m1 = -INFINITY, m2 = -INFINITY, m3 = -INFINITY;
    float l0 = 0.f, l1 = 0.f, l2 = 0.f, l3 = 0.f;
    float4 o = make_float4(0.f, 0.f, 0.f, 0.f);

    for (int base = 0; base < cnt; base += 64) {
        int c = min(64, cnt - base);
        int i = base + lane;
        int s = 0;
        if (i < cnt) s = csr_src[start + i];

        // ---- prefetch first 16 edges' z rows; overlaps es gather + softmax ----
        uint2 zw[16];
#pragma unroll
        for (int u = 0; u < 16; u++) {
            int sj = __shfl(s, u);
            zw[u] = *(const uint2*)&z16[(size_t)sj * 512 + 256 + lane * 4];
        }

        float e0 = -INFINITY, e1 = -INFINITY, e2 = -INFINITY, e3 = -INFINITY;
        if (i < cnt) {
            float4 esv = *(const float4*)&es_ed[(size_t)s * 8];
            float x0 = esv.x + edn.x; e0 = x0 > 0.f ? x0 : SLOPE * x0; if (e0 == 0.f) e0 = NEGV;
            float x1 = esv.y + edn.y; e1 = x1 > 0.f ? x1 : SLOPE * x1; if (e1 == 0.f) e1 = NEGV;
            float x2 = esv.z + edn.z; e2 = x2 > 0.f ? x2 : SLOPE * x2; if (e2 == 0.f) e2 = NEGV;
            float x3 = esv.w + edn.w; e3 = x3 > 0.f ? x3 : SLOPE * x3; if (e3 == 0.f) e3 = NEGV;
        }
        float c0 = e0, c1 = e1, c2 = e2, c3 = e3;
        for (int off = 1; off < 64; off <<= 1) {
            c0 = fmaxf(c0, __shfl_xor(c0, off)); c1 = fmaxf(c1, __shfl_xor(c1, off));
            c2 = fmaxf(c2, __shfl_xor(c2, off)); c3 = fmaxf(c3, __shfl_xor(c3, off));
        }
        float nm0 = fmaxf(m0, c0), nm1 = fmaxf(m1, c1), nm2 = fmaxf(m2, c2), nm3 = fmaxf(m3, c3);
        float sc0 = __expf(m0 - nm0), sc1 = __expf(m1 - nm1);
        float sc2 = __expf(m2 - nm2), sc3 = __expf(m3 - nm3);
        o.x *= sc0; o.y *= sc1; o.z *= sc2; o.w *= sc3;
        l0 *= sc0; l1 *= sc1; l2 *= sc2; l3 *= sc3;
        m0 = nm0; m1 = nm1; m2 = nm2; m3 = nm3;

        float p0 = 0.f, p1 = 0.f, p2 = 0.f, p3 = 0.f;
        if (i < cnt) {
            p0 = __expf(e0 - m0); p1 = __expf(e1 - m1);
            p2 = __expf(e2 - m2); p3 = __expf(e3 - m3);
        }
        l0 += p0; l1 += p1; l2 += p2; l3 += p3;

        // keep prefetch loads alive (rule #17); waits land here, after the softmax chain
#pragma unroll
        for (int u = 0; u < 16; u++)
            asm volatile("" :: "v"(zw[u].x), "v"(zw[u].y));

        int j = 0;
        for (; j + 7 < c; j += 8) {
            float4 pp[8]; half4h zz[8];
#pragma unroll
            for (int u = 0; u < 8; u++) {
                int sj = __shfl(s, j + u);
                pp[u] = make_float4(__shfl(p0, j + u), __shfl(p1, j + u),
                                    __shfl(p2, j + u), __shfl(p3, j + u));
                zz[u] = *(const half4h*)&z16[(size_t)sj * 512 + 256 + lane * 4];
            }
#pragma unroll
            for (int u = 0; u < 8; u++) {
                o.x += pp[u].x * (float)zz[u][0]; o.y += pp[u].y * (float)zz[u][1];
                o.z += pp[u].z * (float)zz[u][2]; o.w += pp[u].w * (float)zz[u][3];
            }
        }
        for (; j < c; ++j) {
            int sj = __shfl(s, j);
            float q0 = __shfl(p0, j), q1 = __shfl(p1, j), q2 = __shfl(p2, j), q3 = __shfl(p3, j);
            half4h zv = *(const half4h*)&z16[(size_t)sj * 512 + 256 + lane * 4];
            o.x += q0 * (float)zv[0]; o.y += q1 * (float)zv[1];
            o.z += q2 * (float)zv[2]; o.w += q3 * (float)zv[3];
        }
    }
    for (int off = 1; off < 64; off <<= 1) {
        l0 += __shfl_xor(l0, off); l1 += __shfl_xor(l1, off);
        l2 += __shfl_xor(l2, off); l3 += __shfl_xor(l3, off);
    }
    if (cnt > 0) { o.x /= l0; o.y /= l1; o.z /= l2; o.w /= l3; }
    size_t ob = (size_t)n * 256;
    __builtin_nontemporal_store(o.x, &out[ob + lane]);
    __builtin_nontemporal_store(o.y, &out[ob + 64 + lane]);
    __builtin_nontemporal_store(o.z, &out[ob + 128 + lane]);
    __builtin_nontemporal_store(o.w, &out[ob + 192 + lane]);
}

extern "C" void kernel_launch(void* const* d_in, const int* in_sizes, int n_in,
                              void* d_out, int out_size, void* d_ws, size_t ws_size,
                              hipStream_t stream) {
    const float* hmat = (const float*)d_in[0];
    const float* W    = (const float*)d_in[1];
    const float* att  = (const float*)d_in[2];
    const int*   src  = (const int*)d_in[3];
    const int*   dst  = (const int*)d_in[4];
    int N = in_sizes[0] / D_IN;
    int E = in_sizes[3];
    float* out = (float*)d_out;

    // workspace layout (16B-aligned); identical to the proven r0/r6 layout, ~113.5 MB
    float* z_t      = (float*)d_ws;                       // N*256 fp32 (fp16 image in-row)
    float* es_ed    = z_t + (size_t)N * 256;              // N*8
    _Float16* Wt_hi = (_Float16*)(es_ed + (size_t)N * 8); // 65536 fp16
    _Float16* Wt_lo = Wt_hi + 65536;                      // 65536 fp16
    int*   counts   = (int*)(Wt_lo + 65536);              // N
    int*   cursor   = counts + N;                         // N (contiguous with counts)
    int*   row_start= cursor + N;                         // N
    int*   bsums    = row_start + N;                      // <=256
    int*   csr_src  = bsums + 256;                        // E

    int NB = (N + 1023) / 1024;

    hipMemsetAsync(counts, 0, (size_t)2 * N * sizeof(int), stream);
    wprep_kernel<<<256, 256, 0, stream>>>(W, Wt_hi, Wt_lo);
    gemm_kernel<<<((N + 127) / 128) * 2, 512, 0, stream>>>(hmat, Wt_hi, Wt_lo, z_t, N);
    esed_kernel<<<(N * 64 + 255) / 256, 256, 0, stream>>>(z_t, att, es_ed, N);
    hist_kernel<<<(E + 255) / 256, 256, 0, stream>>>(dst, counts, E);
    scanA_kernel<<<NB, 256, 0, stream>>>(counts, bsums, N);
    scanB_kernel<<<1, 256, 0, stream>>>(bsums, NB);
    scanC_kernel<<<NB, 256, 0, stream>>>(counts, bsums, row_start, N);
    scatter_kernel<<<(E + 255) / 256, 256, 0, stream>>>(src, dst, row_start, cursor, csr_src, E);
    aggregate_kernel<<<(N * 64 + 255) / 256, 256, 0, stream>>>((const _Float16*)z_t, es_ed, csr_src, row_start, counts, out, N);
}

// Round 8
// 586.139 us; speedup vs baseline: 1.0570x; 1.0570x over previous
//
#include <hip/hip_runtime.h>
#include <math.h>

#define NEGV (-1000.0f)
#define SLOPE 0.01f
#define D_IN 256
#define LDK 72

typedef _Float16 half8 __attribute__((ext_vector_type(8)));
typedef _Float16 half4h __attribute__((ext_vector_type(4)));
typedef float f32x4 __attribute__((ext_vector_type(4)));

// ---------- W prep: W[h][k][f] fp32 -> split fp16 Wt_hi/Wt_lo[c][k], c=f*4+h ----------
__global__ void wprep_kernel(const float* __restrict__ W, _Float16* __restrict__ Wt_hi,
                             _Float16* __restrict__ Wt_lo) {
    int i = blockIdx.x * 256 + threadIdx.x;   // 65536, input-coalesced
    int f = i & 63;
    int k = (i >> 6) & 255;
    int h = i >> 14;
    float w = W[i];
    _Float16 hi = (_Float16)w;
    _Float16 lo = (_Float16)(w - (float)hi);
    int c = f * 4 + h;
    Wt_hi[c * 256 + k] = hi;
    Wt_lo[c * 256 + k] = lo;
}

// ---------- split-fp16 MFMA GEMM: z_t[n][c] = sum_k h[n][k]*Wt[c][k], fp32 out ----------
// (byte-identical to the proven r0 GEMM)
// BM=128, BN=128, BK=64; 512 thr = 8 waves; wave w: rows (w&3)*32 (2 tiles), cols (w>>2)*64 (4 tiles)
__global__ __launch_bounds__(512) void gemm_kernel(const float* __restrict__ hmat,
        const _Float16* __restrict__ Wt_hi, const _Float16* __restrict__ Wt_lo,
        float* __restrict__ z_t, int N) {
    __shared__ __align__(16) _Float16 smem[4 * 128 * LDK];   // 73728 B
    _Float16* A_hi = smem;
    _Float16* A_lo = smem + 128 * LDK;
    _Float16* B_hi = smem + 2 * 128 * LDK;
    _Float16* B_lo = smem + 3 * 128 * LDK;
    const int t = threadIdx.x;
    const int lane = t & 63;
    const int w = t >> 6;
    const int quad = lane >> 4;
    const int m16 = lane & 15;
    const int rg = w & 3;
    const int cg = w >> 2;
    const int n0 = (blockIdx.x >> 1) * 128;
    const int c0 = (blockIdx.x & 1) * 128;

    f32x4 acc[2][4];
#pragma unroll
    for (int rt = 0; rt < 2; rt++)
#pragma unroll
        for (int ct = 0; ct < 4; ct++) acc[rt][ct] = (f32x4){0.f, 0.f, 0.f, 0.f};

    for (int kc = 0; kc < 256; kc += 64) {
        __syncthreads();
        // stage A: 128 rows x 64 k, fp32 -> hi/lo fp16
#pragma unroll
        for (int i = 0; i < 4; i++) {
            int idx = i * 512 + t;                    // 0..2047
            int row = idx >> 4, q = idx & 15;
            int rr = min(n0 + row, N - 1);            // clamp; garbage rows masked at store
            float4 v = *(const float4*)&hmat[(size_t)rr * 256 + kc + q * 4];
            half4h hv, lv;
            hv[0] = (_Float16)v.x; lv[0] = (_Float16)(v.x - (float)hv[0]);
            hv[1] = (_Float16)v.y; lv[1] = (_Float16)(v.y - (float)hv[1]);
            hv[2] = (_Float16)v.z; lv[2] = (_Float16)(v.z - (float)hv[2]);
            hv[3] = (_Float16)v.w; lv[3] = (_Float16)(v.w - (float)hv[3]);
            *(half4h*)&A_hi[row * LDK + q * 4] = hv;
            *(half4h*)&A_lo[row * LDK + q * 4] = lv;
        }
        // stage B: 128 c x 64 k fp16 hi/lo
#pragma unroll
        for (int i = 0; i < 2; i++) {
            int idx = i * 512 + t;                    // 0..1023
            int c = idx >> 3, seg = idx & 7;
            float4 vh = *(const float4*)&Wt_hi[(c0 + c) * 256 + kc + seg * 8];
            float4 vl = *(const float4*)&Wt_lo[(c0 + c) * 256 + kc + seg * 8];
            *(float4*)&B_hi[c * LDK + seg * 8] = vh;
            *(float4*)&B_lo[c * LDK + seg * 8] = vl;
        }
        __syncthreads();
#pragma unroll
        for (int ks = 0; ks < 2; ks++) {
            half8 ah[2], al[2], bh[4], bl[4];
#pragma unroll
            for (int rt = 0; rt < 2; rt++) {
                int ro = ((rg * 2 + rt) * 16 + m16) * LDK + ks * 32 + quad * 8;
                ah[rt] = *(const half8*)&A_hi[ro];
                al[rt] = *(const half8*)&A_lo[ro];
            }
#pragma unroll
            for (int ct = 0; ct < 4; ct++) {
                int co = ((cg * 4 + ct) * 16 + m16) * LDK + ks * 32 + quad * 8;
                bh[ct] = *(const half8*)&B_hi[co];
                bl[ct] = *(const half8*)&B_lo[co];
            }
#pragma unroll
            for (int rt = 0; rt < 2; rt++)
#pragma unroll
                for (int ct = 0; ct < 4; ct++) {
                    acc[rt][ct] = __builtin_amdgcn_mfma_f32_16x16x32_f16(ah[rt], bh[ct], acc[rt][ct], 0, 0, 0);
                    acc[rt][ct] = __builtin_amdgcn_mfma_f32_16x16x32_f16(al[rt], bh[ct], acc[rt][ct], 0, 0, 0);
                    acc[rt][ct] = __builtin_amdgcn_mfma_f32_16x16x32_f16(ah[rt], bl[ct], acc[rt][ct], 0, 0, 0);
                }
        }
    }
    // epilogue: C/D col=lane&15, row=quad*4+reg; direct fp32 stores (16-lane coalesced)
#pragma unroll
    for (int rt = 0; rt < 2; rt++)
#pragma unroll
        for (int ct = 0; ct < 4; ct++)
#pragma unroll
            for (int r = 0; r < 4; r++) {
                int n = n0 + rg * 32 + rt * 16 + quad * 4 + r;
                int c = c0 + cg * 64 + ct * 16 + m16;
                if (n < N) z_t[(size_t)n * 256 + c] = acc[rt][ct][r];
            }
}

// ---------- es/ed per node (fp32 z) + in-row fp16 z image for the aggregation ----------
// Each z_t row is 1024 B of fp32. After the full row is loaded (one wave = one row),
// the fp16 image of the row (512 B) is written into bytes [512,1024) of the SAME row,
// overwriting fp32 halves already consumed. Single writer per byte; no cross-row hazard.
__global__ void esed_kernel(float* __restrict__ z_t, const float* __restrict__ att,
                            float* __restrict__ es_ed, int N) {
    int gid = blockIdx.x * blockDim.x + threadIdx.x;
    int n = gid >> 6;
    int lane = gid & 63;
    if (n >= N) return;
    float4 zv = *(const float4*)&z_t[(size_t)n * 256 + lane * 4];
    float ps0 = zv.x * att[0 * 128 + lane];
    float ps1 = zv.y * att[1 * 128 + lane];
    float ps2 = zv.z * att[2 * 128 + lane];
    float ps3 = zv.w * att[3 * 128 + lane];
    float pd0 = zv.x * att[0 * 128 + 64 + lane];
    float pd1 = zv.y * att[1 * 128 + 64 + lane];
    float pd2 = zv.z * att[2 * 128 + 64 + lane];
    float pd3 = zv.w * att[3 * 128 + 64 + lane];
    for (int off = 1; off < 64; off <<= 1) {
        ps0 += __shfl_xor(ps0, off); ps1 += __shfl_xor(ps1, off);
        ps2 += __shfl_xor(ps2, off); ps3 += __shfl_xor(ps3, off);
        pd0 += __shfl_xor(pd0, off); pd1 += __shfl_xor(pd1, off);
        pd2 += __shfl_xor(pd2, off); pd3 += __shfl_xor(pd3, off);
    }
    // fp16 image: half index n*512 + 256 + lane*4  (= byte n*1024 + 512 + lane*8)
    half4h h16;
    h16[0] = (_Float16)zv.x; h16[1] = (_Float16)zv.y;
    h16[2] = (_Float16)zv.z; h16[3] = (_Float16)zv.w;
    *(half4h*)((_Float16*)z_t + (size_t)n * 512 + 256 + lane * 4) = h16;
    if (lane == 0) {
        *(float4*)&es_ed[(size_t)n * 8]     = make_float4(ps0, ps1, ps2, ps3);
        *(float4*)&es_ed[(size_t)n * 8 + 4] = make_float4(pd0, pd1, pd2, pd3);
    }
}

// ---------- CSR build ----------
__global__ void hist_kernel(const int* __restrict__ dst, int* __restrict__ counts, int E) {
    int i = blockIdx.x * blockDim.x + threadIdx.x;
    if (i < E) atomicAdd(&counts[dst[i]], 1);
}

__global__ void scanA_kernel(const int* __restrict__ counts, int* __restrict__ bsums, int N) {
    __shared__ int lds[256];
    int t = threadIdx.x;
    int base = blockIdx.x * 1024 + t * 4;
    int s = 0;
    if (base + 3 < N) {
        int4 v = *(const int4*)&counts[base];
        s = v.x + v.y + v.z + v.w;
    } else {
        for (int u = 0; u < 4; u++) if (base + u < N) s += counts[base + u];
    }
    lds[t] = s; __syncthreads();
    for (int off = 128; off > 0; off >>= 1) {
        if (t < off) lds[t] += lds[t + off];
        __syncthreads();
    }
    if (t == 0) bsums[blockIdx.x] = lds[0];
}

__global__ void scanB_kernel(int* __restrict__ bsums, int nb) {
    __shared__ int lds[256];
    int t = threadIdx.x;
    int v = (t < nb) ? bsums[t] : 0;
    lds[t] = v; __syncthreads();
    for (int off = 1; off < 256; off <<= 1) {
        int x = (t >= off) ? lds[t - off] : 0;
        __syncthreads();
        lds[t] += x;
        __syncthreads();
    }
    if (t < nb) bsums[t] = lds[t] - v;   // exclusive
}

__global__ void scanC_kernel(const int* __restrict__ counts, const int* __restrict__ bsums,
                             int* __restrict__ row_start, int N) {
    __shared__ int lds[256];
    int t = threadIdx.x;
    int base = blockIdx.x * 1024 + t * 4;
    int4 v = make_int4(0, 0, 0, 0);
    if (base + 3 < N) v = *(const int4*)&counts[base];
    else {
        if (base + 0 < N) v.x = counts[base + 0];
        if (base + 1 < N) v.y = counts[base + 1];
        if (base + 2 < N) v.z = counts[base + 2];
    }
    int s = v.x + v.y + v.z + v.w;
    lds[t] = s; __syncthreads();
    for (int off = 1; off < 256; off <<= 1) {
        int x = (t >= off) ? lds[t - off] : 0;
        __syncthreads();
        lds[t] += x;
        __syncthreads();
    }
    int excl = lds[t] - s + bsums[blockIdx.x];
    int4 r;
    r.x = excl; r.y = r.x + v.x; r.z = r.y + v.y; r.w = r.z + v.z;
    if (base + 3 < N) *(int4*)&row_start[base] = r;
    else {
        if (base + 0 < N) row_start[base + 0] = r.x;
        if (base + 1 < N) row_start[base + 1] = r.y;
        if (base + 2 < N) row_start[base + 2] = r.z;
    }
}

__global__ void scatter_kernel(const int* __restrict__ src, const int* __restrict__ dst,
                               const int* __restrict__ row_start, int* __restrict__ cursor,
                               int* __restrict__ csr_src, int E) {
    int i = blockIdx.x * blockDim.x + threadIdx.x;
    if (i < E) {
        int d = dst[i];
        int pos = row_start[d] + atomicAdd(&cursor[d], 1);
        csr_src[pos] = src[i];
    }
}

// ---------- aggregation: one wave per node, online softmax, fp16 in-row z gathers ----------
// z16 = (const _Float16*)z_t; row n's fp16 image lives at half index n*512 + 256.
// Inner loop: 16-wide issue-all-then-consume batches (2x MLP vs 8-wide serial batches;
// no duplicate loads, loads adjacent to consumers so no sink hazard). Per-edge FMA
// order identical to r6 -> bit-identical output.
__global__ __launch_bounds__(256) void aggregate_kernel(const _Float16* __restrict__ z16,
        const float* __restrict__ es_ed, const int* __restrict__ csr_src,
        const int* __restrict__ row_start, const int* __restrict__ counts,
        float* __restrict__ out, int N) {
    int gid = blockIdx.x * blockDim.x + threadIdx.x;
    int n = gid >> 6;
    int lane = gid & 63;   // = f
    if (n >= N) return;
    int cnt = counts[n];
    int start = row_start[n];
    float4 edn = *(const float4*)&es_ed[(size_t)n * 8 + 4];

    float m0 = -INFINITY, m1 = -INFINITY, m2 = -INFINITY, m3 = -INFINITY;
    float l0 = 0.f, l1 = 0.f, l2 = 0.f, l3 = 0.f;
    float4 o = make_float4(0.f, 0.f, 0.f, 0.f);

    for (int base = 0; base < cnt; base += 64) {
        int c = min(64, cnt - base);
        int i = base + lane;
        int s = 0;
        float e0 = -INFINITY, e1 = -INFINITY, e2 = -INFINITY, e3 = -INFINITY;
        if (i < cnt) {
            s = csr_src[start + i];
            float4 esv = *(const float4*)&es_ed[(size_t)s * 8];
            float x0 = esv.x + edn.x; e0 = x0 > 0.f ? x0 : SLOPE * x0; if (e0 == 0.f) e0 = NEGV;
            float x1 = esv.y + edn.y; e1 = x1 > 0.f ? x1 : SLOPE * x1; if (e1 == 0.f) e1 = NEGV;
            float x2 = esv.z + edn.z; e2 = x2 > 0.f ? x2 : SLOPE * x2; if (e2 == 0.f) e2 = NEGV;
            float x3 = esv.w + edn.w; e3 = x3 > 0.f ? x3 : SLOPE * x3; if (e3 == 0.f) e3 = NEGV;
        }
        float c0 = e0, c1 = e1, c2 = e2, c3 = e3;
        for (int off = 1; off < 64; off <<= 1) {
            c0 = fmaxf(c0, __shfl_xor(c0, off)); c1 = fmaxf(c1, __shfl_xor(c1, off));
            c2 = fmaxf(c2, __shfl_xor(c2, off)); c3 = fmaxf(c3, __shfl_xor(c3, off));
        }
        float nm0 = fmaxf(m0, c0), nm1 = fmaxf(m1, c1), nm2 = fmaxf(m2, c2), nm3 = fmaxf(m3, c3);
        float sc0 = __expf(m0 - nm0), sc1 = __expf(m1 - nm1);
        float sc2 = __expf(m2 - nm2), sc3 = __expf(m3 - nm3);
        o.x *= sc0; o.y *= sc1; o.z *= sc2; o.w *= sc3;
        l0 *= sc0; l1 *= sc1; l2 *= sc2; l3 *= sc3;
        m0 = nm0; m1 = nm1; m2 = nm2; m3 = nm3;

        float p0 = 0.f, p1 = 0.f, p2 = 0.f, p3 = 0.f;
        if (i < cnt) {
            p0 = __expf(e0 - m0); p1 = __expf(e1 - m1);
            p2 = __expf(e2 - m2); p3 = __expf(e3 - m3);
        }
        l0 += p0; l1 += p1; l2 += p2; l3 += p3;

        int j = 0;
        for (; j + 15 < c; j += 16) {
            half4h zz[16];
#pragma unroll
            for (int u = 0; u < 16; u++) {
                int sj = __shfl(s, j + u);
                zz[u] = *(const half4h*)&z16[(size_t)sj * 512 + 256 + lane * 4];
            }
#pragma unroll
            for (int u = 0; u < 16; u++) {
                float q0 = __shfl(p0, j + u), q1 = __shfl(p1, j + u);
                float q2 = __shfl(p2, j + u), q3 = __shfl(p3, j + u);
                o.x += q0 * (float)zz[u][0]; o.y += q1 * (float)zz[u][1];
                o.z += q2 * (float)zz[u][2]; o.w += q3 * (float)zz[u][3];
            }
        }
        for (; j + 7 < c; j += 8) {
            half4h zz[8];
#pragma unroll
            for (int u = 0; u < 8; u++) {
                int sj = __shfl(s, j + u);
                zz[u] = *(const half4h*)&z16[(size_t)sj * 512 + 256 + lane * 4];
            }
#pragma unroll
            for (int u = 0; u < 8; u++) {
                float q0 = __shfl(p0, j + u), q1 = __shfl(p1, j + u);
                float q2 = __shfl(p2, j + u), q3 = __shfl(p3, j + u);
                o.x += q0 * (float)zz[u][0]; o.y += q1 * (float)zz[u][1];
                o.z += q2 * (float)zz[u][2]; o.w += q3 * (float)zz[u][3];
            }
        }
        for (; j < c; ++j) {
            int sj = __shfl(s, j);
            float q0 = __shfl(p0, j), q1 = __shfl(p1, j), q2 = __shfl(p2, j), q3 = __shfl(p3, j);
            half4h zv = *(const half4h*)&z16[(size_t)sj * 512 + 256 + lane * 4];
            o.x += q0 * (float)zv[0]; o.y += q1 * (float)zv[1];
            o.z += q2 * (float)zv[2]; o.w += q3 * (float)zv[3];
        }
    }
    for (int off = 1; off < 64; off <<= 1) {
        l0 += __shfl_xor(l0, off); l1 += __shfl_xor(l1, off);
        l2 += __shfl_xor(l2, off); l3 += __shfl_xor(l3, off);
    }
    if (cnt > 0) { o.x /= l0; o.y /= l1; o.z /= l2; o.w /= l3; }
    size_t ob = (size_t)n * 256;
    __builtin_nontemporal_store(o.x, &out[ob + lane]);
    __builtin_nontemporal_store(o.y, &out[ob + 64 + lane]);
    __builtin_nontemporal_store(o.z, &out[ob + 128 + lane]);
    __builtin_nontemporal_store(o.w, &out[ob + 192 + lane]);
}

extern "C" void kernel_launch(void* const* d_in, const int* in_sizes, int n_in,
                              void* d_out, int out_size, void* d_ws, size_t ws_size,
                              hipStream_t stream) {
    const float* hmat = (const float*)d_in[0];
    const float* W    = (const float*)d_in[1];
    const float* att  = (const float*)d_in[2];
    const int*   src  = (const int*)d_in[3];
    const int*   dst  = (const int*)d_in[4];
    int N = in_sizes[0] / D_IN;
    int E = in_sizes[3];
    float* out = (float*)d_out;

    // workspace layout (16B-aligned); identical to the proven r0/r6 layout, ~113.5 MB
    float* z_t      = (float*)d_ws;                       // N*256 fp32 (fp16 image in-row)
    float* es_ed    = z_t + (size_t)N * 256;              // N*8
    _Float16* Wt_hi = (_Float16*)(es_ed + (size_t)N * 8); // 65536 fp16
    _Float16* Wt_lo = Wt_hi + 65536;                      // 65536 fp16
    int*   counts   = (int*)(Wt_lo + 65536);              // N
    int*   cursor   = counts + N;                         // N (contiguous with counts)
    int*   row_start= cursor + N;                         // N
    int*   bsums    = row_start + N;                      // <=256
    int*   csr_src  = bsums + 256;                        // E

    int NB = (N + 1023) / 1024;

    hipMemsetAsync(counts, 0, (size_t)2 * N * sizeof(int), stream);
    wprep_kernel<<<256, 256, 0, stream>>>(W, Wt_hi, Wt_lo);
    gemm_kernel<<<((N + 127) / 128) * 2, 512, 0, stream>>>(hmat, Wt_hi, Wt_lo, z_t, N);
    esed_kernel<<<(N * 64 + 255) / 256, 256, 0, stream>>>(z_t, att, es_ed, N);
    hist_kernel<<<(E + 255) / 256, 256, 0, stream>>>(dst, counts, E);
    scanA_kernel<<<NB, 256, 0, stream>>>(counts, bsums, N);
    scanB_kernel<<<1, 256, 0, stream>>>(bsums, NB);
    scanC_kernel<<<NB, 256, 0, stream>>>(counts, bsums, row_start, N);
    scatter_kernel<<<(E + 255) / 256, 256, 0, stream>>>(src, dst, row_start, cursor, csr_src, E);
    aggregate_kernel<<<(N * 64 + 255) / 256, 256, 0, stream>>>((const _Float16*)z_t, es_ed, csr_src, row_start, counts, out, N);
}

// Round 9
// 565.932 us; speedup vs baseline: 1.0948x; 1.0357x over previous
//
#include <hip/hip_runtime.h>
#include <math.h>

#define NEGV (-1000.0f)
#define SLOPE 0.01f
#define D_IN 256
#define LDK 72

typedef _Float16 half8 __attribute__((ext_vector_type(8)));
typedef _Float16 half4h __attribute__((ext_vector_type(4)));
typedef float f32x4 __attribute__((ext_vector_type(4)));

// SALU broadcast from a wave-uniform lane index: v_readlane, no LDS-pipe traffic
// (bit-identical to __shfl(x, l) for uniform l).
__device__ __forceinline__ float rlf(float v, int l) {
    return __builtin_bit_cast(float, __builtin_amdgcn_readlane(__builtin_bit_cast(int, v), l));
}
__device__ __forceinline__ int rli(int v, int l) {
    return __builtin_amdgcn_readlane(v, l);
}

// ---------- W prep: W[h][k][f] fp32 -> split fp16 Wt_hi/Wt_lo[c][k], c=f*4+h ----------
__global__ void wprep_kernel(const float* __restrict__ W, _Float16* __restrict__ Wt_hi,
                             _Float16* __restrict__ Wt_lo) {
    int i = blockIdx.x * 256 + threadIdx.x;   // 65536, input-coalesced
    int f = i & 63;
    int k = (i >> 6) & 255;
    int h = i >> 14;
    float w = W[i];
    _Float16 hi = (_Float16)w;
    _Float16 lo = (_Float16)(w - (float)hi);
    int c = f * 4 + h;
    Wt_hi[c * 256 + k] = hi;
    Wt_lo[c * 256 + k] = lo;
}

// ---------- split-fp16 MFMA GEMM: z_t[n][c] = sum_k h[n][k]*Wt[c][k], fp32 out ----------
// (byte-identical to the proven r0 GEMM)
// BM=128, BN=128, BK=64; 512 thr = 8 waves; wave w: rows (w&3)*32 (2 tiles), cols (w>>2)*64 (4 tiles)
__global__ __launch_bounds__(512) void gemm_kernel(const float* __restrict__ hmat,
        const _Float16* __restrict__ Wt_hi, const _Float16* __restrict__ Wt_lo,
        float* __restrict__ z_t, int N) {
    __shared__ __align__(16) _Float16 smem[4 * 128 * LDK];   // 73728 B
    _Float16* A_hi = smem;
    _Float16* A_lo = smem + 128 * LDK;
    _Float16* B_hi = smem + 2 * 128 * LDK;
    _Float16* B_lo = smem + 3 * 128 * LDK;
    const int t = threadIdx.x;
    const int lane = t & 63;
    const int w = t >> 6;
    const int quad = lane >> 4;
    const int m16 = lane & 15;
    const int rg = w & 3;
    const int cg = w >> 2;
    const int n0 = (blockIdx.x >> 1) * 128;
    const int c0 = (blockIdx.x & 1) * 128;

    f32x4 acc[2][4];
#pragma unroll
    for (int rt = 0; rt < 2; rt++)
#pragma unroll
        for (int ct = 0; ct < 4; ct++) acc[rt][ct] = (f32x4){0.f, 0.f, 0.f, 0.f};

    for (int kc = 0; kc < 256; kc += 64) {
        __syncthreads();
        // stage A: 128 rows x 64 k, fp32 -> hi/lo fp16
#pragma unroll
        for (int i = 0; i < 4; i++) {
            int idx = i * 512 + t;                    // 0..2047
            int row = idx >> 4, q = idx & 15;
            int rr = min(n0 + row, N - 1);            // clamp; garbage rows masked at store
            float4 v = *(const float4*)&hmat[(size_t)rr * 256 + kc + q * 4];
            half4h hv, lv;
            hv[0] = (_Float16)v.x; lv[0] = (_Float16)(v.x - (float)hv[0]);
            hv[1] = (_Float16)v.y; lv[1] = (_Float16)(v.y - (float)hv[1]);
            hv[2] = (_Float16)v.z; lv[2] = (_Float16)(v.z - (float)hv[2]);
            hv[3] = (_Float16)v.w; lv[3] = (_Float16)(v.w - (float)hv[3]);
            *(half4h*)&A_hi[row * LDK + q * 4] = hv;
            *(half4h*)&A_lo[row * LDK + q * 4] = lv;
        }
        // stage B: 128 c x 64 k fp16 hi/lo
#pragma unroll
        for (int i = 0; i < 2; i++) {
            int idx = i * 512 + t;                    // 0..1023
            int c = idx >> 3, seg = idx & 7;
            float4 vh = *(const float4*)&Wt_hi[(c0 + c) * 256 + kc + seg * 8];
            float4 vl = *(const float4*)&Wt_lo[(c0 + c) * 256 + kc + seg * 8];
            *(float4*)&B_hi[c * LDK + seg * 8] = vh;
            *(float4*)&B_lo[c * LDK + seg * 8] = vl;
        }
        __syncthreads();
#pragma unroll
        for (int ks = 0; ks < 2; ks++) {
            half8 ah[2], al[2], bh[4], bl[4];
#pragma unroll
            for (int rt = 0; rt < 2; rt++) {
                int ro = ((rg * 2 + rt) * 16 + m16) * LDK + ks * 32 + quad * 8;
                ah[rt] = *(const half8*)&A_hi[ro];
                al[rt] = *(const half8*)&A_lo[ro];
            }
#pragma unroll
            for (int ct = 0; ct < 4; ct++) {
                int co = ((cg * 4 + ct) * 16 + m16) * LDK + ks * 32 + quad * 8;
                bh[ct] = *(const half8*)&B_hi[co];
                bl[ct] = *(const half8*)&B_lo[co];
            }
#pragma unroll
            for (int rt = 0; rt < 2; rt++)
#pragma unroll
                for (int ct = 0; ct < 4; ct++) {
                    acc[rt][ct] = __builtin_amdgcn_mfma_f32_16x16x32_f16(ah[rt], bh[ct], acc[rt][ct], 0, 0, 0);
                    acc[rt][ct] = __builtin_amdgcn_mfma_f32_16x16x32_f16(al[rt], bh[ct], acc[rt][ct], 0, 0, 0);
                    acc[rt][ct] = __builtin_amdgcn_mfma_f32_16x16x32_f16(ah[rt], bl[ct], acc[rt][ct], 0, 0, 0);
                }
        }
    }
    // epilogue: C/D col=lane&15, row=quad*4+reg; direct fp32 stores (16-lane coalesced)
#pragma unroll
    for (int rt = 0; rt < 2; rt++)
#pragma unroll
        for (int ct = 0; ct < 4; ct++)
#pragma unroll
            for (int r = 0; r < 4; r++) {
                int n = n0 + rg * 32 + rt * 16 + quad * 4 + r;
                int c = c0 + cg * 64 + ct * 16 + m16;
                if (n < N) z_t[(size_t)n * 256 + c] = acc[rt][ct][r];
            }
}

// ---------- es/ed per node (fp32 z) + in-row fp16 z image for the aggregation ----------
// Each z_t row is 1024 B of fp32. After the full row is loaded (one wave = one row),
// the fp16 image of the row (512 B) is written into bytes [512,1024) of the SAME row,
// overwriting fp32 halves already consumed. Single writer per byte; no cross-row hazard.
__global__ void esed_kernel(float* __restrict__ z_t, const float* __restrict__ att,
                            float* __restrict__ es_ed, int N) {
    int gid = blockIdx.x * blockDim.x + threadIdx.x;
    int n = gid >> 6;
    int lane = gid & 63;
    if (n >= N) return;
    float4 zv = *(const float4*)&z_t[(size_t)n * 256 + lane * 4];
    float ps0 = zv.x * att[0 * 128 + lane];
    float ps1 = zv.y * att[1 * 128 + lane];
    float ps2 = zv.z * att[2 * 128 + lane];
    float ps3 = zv.w * att[3 * 128 + lane];
    float pd0 = zv.x * att[0 * 128 + 64 + lane];
    float pd1 = zv.y * att[1 * 128 + 64 + lane];
    float pd2 = zv.z * att[2 * 128 + 64 + lane];
    float pd3 = zv.w * att[3 * 128 + 64 + lane];
    for (int off = 1; off < 64; off <<= 1) {
        ps0 += __shfl_xor(ps0, off); ps1 += __shfl_xor(ps1, off);
        ps2 += __shfl_xor(ps2, off); ps3 += __shfl_xor(ps3, off);
        pd0 += __shfl_xor(pd0, off); pd1 += __shfl_xor(pd1, off);
        pd2 += __shfl_xor(pd2, off); pd3 += __shfl_xor(pd3, off);
    }
    // fp16 image: half index n*512 + 256 + lane*4  (= byte n*1024 + 512 + lane*8)
    half4h h16;
    h16[0] = (_Float16)zv.x; h16[1] = (_Float16)zv.y;
    h16[2] = (_Float16)zv.z; h16[3] = (_Float16)zv.w;
    *(half4h*)((_Float16*)z_t + (size_t)n * 512 + 256 + lane * 4) = h16;
    if (lane == 0) {
        *(float4*)&es_ed[(size_t)n * 8]     = make_float4(ps0, ps1, ps2, ps3);
        *(float4*)&es_ed[(size_t)n * 8 + 4] = make_float4(pd0, pd1, pd2, pd3);
    }
}

// ---------- CSR build ----------
__global__ void hist_kernel(const int* __restrict__ dst, int* __restrict__ counts, int E) {
    int i = blockIdx.x * blockDim.x + threadIdx.x;
    if (i < E) atomicAdd(&counts[dst[i]], 1);
}

__global__ void scanA_kernel(const int* __restrict__ counts, int* __restrict__ bsums, int N) {
    __shared__ int lds[256];
    int t = threadIdx.x;
    int base = blockIdx.x * 1024 + t * 4;
    int s = 0;
    if (base + 3 < N) {
        int4 v = *(const int4*)&counts[base];
        s = v.x + v.y + v.z + v.w;
    } else {
        for (int u = 0; u < 4; u++) if (base + u < N) s += counts[base + u];
    }
    lds[t] = s; __syncthreads();
    for (int off = 128; off > 0; off >>= 1) {
        if (t < off) lds[t] += lds[t + off];
        __syncthreads();
    }
    if (t == 0) bsums[blockIdx.x] = lds[0];
}

__global__ void scanB_kernel(int* __restrict__ bsums, int nb) {
    __shared__ int lds[256];
    int t = threadIdx.x;
    int v = (t < nb) ? bsums[t] : 0;
    lds[t] = v; __syncthreads();
    for (int off = 1; off < 256; off <<= 1) {
        int x = (t >= off) ? lds[t - off] : 0;
        __syncthreads();
        lds[t] += x;
        __syncthreads();
    }
    if (t < nb) bsums[t] = lds[t] - v;   // exclusive
}

__global__ void scanC_kernel(const int* __restrict__ counts, const int* __restrict__ bsums,
                             int* __restrict__ row_start, int N) {
    __shared__ int lds[256];
    int t = threadIdx.x;
    int base = blockIdx.x * 1024 + t * 4;
    int4 v = make_int4(0, 0, 0, 0);
    if (base + 3 < N) v = *(const int4*)&counts[base];
    else {
        if (base + 0 < N) v.x = counts[base + 0];
        if (base + 1 < N) v.y = counts[base + 1];
        if (base + 2 < N) v.z = counts[base + 2];
    }
    int s = v.x + v.y + v.z + v.w;
    lds[t] = s; __syncthreads();
    for (int off = 1; off < 256; off <<= 1) {
        int x = (t >= off) ? lds[t - off] : 0;
        __syncthreads();
        lds[t] += x;
        __syncthreads();
    }
    int excl = lds[t] - s + bsums[blockIdx.x];
    int4 r;
    r.x = excl; r.y = r.x + v.x; r.z = r.y + v.y; r.w = r.z + v.z;
    if (base + 3 < N) *(int4*)&row_start[base] = r;
    else {
        if (base + 0 < N) row_start[base + 0] = r.x;
        if (base + 1 < N) row_start[base + 1] = r.y;
        if (base + 2 < N) row_start[base + 2] = r.z;
    }
}

__global__ void scatter_kernel(const int* __restrict__ src, const int* __restrict__ dst,
                               const int* __restrict__ row_start, int* __restrict__ cursor,
                               int* __restrict__ csr_src, int E) {
    int i = blockIdx.x * blockDim.x + threadIdx.x;
    if (i < E) {
        int d = dst[i];
        int pos = row_start[d] + atomicAdd(&cursor[d], 1);
        csr_src[pos] = src[i];
    }
}

// ---------- aggregation: one wave per node, online softmax, fp16 in-row z gathers ----------
// z16 = (const _Float16*)z_t; row n's fp16 image lives at half index n*512 + 256.
// Per-edge broadcasts (s, p0..p3 from a wave-uniform lane) use v_readlane (SALU pipe)
// instead of __shfl (ds_bpermute, LDS pipe): ~80 DS ops/node -> 0 in the inner loop.
// Butterfly reductions (genuinely per-lane-different) remain shuffles.
__global__ __launch_bounds__(256) void aggregate_kernel(const _Float16* __restrict__ z16,
        const float* __restrict__ es_ed, const int* __restrict__ csr_src,
        const int* __restrict__ row_start, const int* __restrict__ counts,
        float* __restrict__ out, int N) {
    int gid = blockIdx.x * blockDim.x + threadIdx.x;
    int n = gid >> 6;
    int lane = gid & 63;   // = f
    if (n >= N) return;
    int cnt = counts[n];
    int start = row_start[n];
    float4 edn = *(const float4*)&es_ed[(size_t)n * 8 + 4];

    float m0 = -INFINITY, m1 = -INFINITY, m2 = -INFINITY, m3 = -INFINITY;
    float l0 = 0.f, l1 = 0.f, l2 = 0.f, l3 = 0.f;
    float4 o = make_float4(0.f, 0.f, 0.f, 0.f);

    for (int base = 0; base < cnt; base += 64) {
        int c = min(64, cnt - base);
        int i = base + lane;
        int s = 0;
        float e0 = -INFINITY, e1 = -INFINITY, e2 = -INFINITY, e3 = -INFINITY;
        if (i < cnt) {
            s = csr_src[start + i];
            float4 esv = *(const float4*)&es_ed[(size_t)s * 8];
            float x0 = esv.x + edn.x; e0 = x0 > 0.f ? x0 : SLOPE * x0; if (e0 == 0.f) e0 = NEGV;
            float x1 = esv.y + edn.y; e1 = x1 > 0.f ? x1 : SLOPE * x1; if (e1 == 0.f) e1 = NEGV;
            float x2 = esv.z + edn.z; e2 = x2 > 0.f ? x2 : SLOPE * x2; if (e2 == 0.f) e2 = NEGV;
            float x3 = esv.w + edn.w; e3 = x3 > 0.f ? x3 : SLOPE * x3; if (e3 == 0.f) e3 = NEGV;
        }
        float c0 = e0, c1 = e1, c2 = e2, c3 = e3;
        for (int off = 1; off < 64; off <<= 1) {
            c0 = fmaxf(c0, __shfl_xor(c0, off)); c1 = fmaxf(c1, __shfl_xor(c1, off));
            c2 = fmaxf(c2, __shfl_xor(c2, off)); c3 = fmaxf(c3, __shfl_xor(c3, off));
        }
        float nm0 = fmaxf(m0, c0), nm1 = fmaxf(m1, c1), nm2 = fmaxf(m2, c2), nm3 = fmaxf(m3, c3);
        float sc0 = __expf(m0 - nm0), sc1 = __expf(m1 - nm1);
        float sc2 = __expf(m2 - nm2), sc3 = __expf(m3 - nm3);
        o.x *= sc0; o.y *= sc1; o.z *= sc2; o.w *= sc3;
        l0 *= sc0; l1 *= sc1; l2 *= sc2; l3 *= sc3;
        m0 = nm0; m1 = nm1; m2 = nm2; m3 = nm3;

        float p0 = 0.f, p1 = 0.f, p2 = 0.f, p3 = 0.f;
        if (i < cnt) {
            p0 = __expf(e0 - m0); p1 = __expf(e1 - m1);
            p2 = __expf(e2 - m2); p3 = __expf(e3 - m3);
        }
        l0 += p0; l1 += p1; l2 += p2; l3 += p3;

        int j = 0;
        for (; j + 7 < c; j += 8) {
            float4 pp[8]; half4h zz[8];
#pragma unroll
            for (int u = 0; u < 8; u++) {
                int sj = rli(s, j + u);
                pp[u] = make_float4(rlf(p0, j + u), rlf(p1, j + u),
                                    rlf(p2, j + u), rlf(p3, j + u));
                zz[u] = *(const half4h*)&z16[(size_t)sj * 512 + 256 + lane * 4];
            }
#pragma unroll
            for (int u = 0; u < 8; u++) {
                o.x += pp[u].x * (float)zz[u][0]; o.y += pp[u].y * (float)zz[u][1];
                o.z += pp[u].z * (float)zz[u][2]; o.w += pp[u].w * (float)zz[u][3];
            }
        }
        for (; j < c; ++j) {
            int sj = rli(s, j);
            float q0 = rlf(p0, j), q1 = rlf(p1, j), q2 = rlf(p2, j), q3 = rlf(p3, j);
            half4h zv = *(const half4h*)&z16[(size_t)sj * 512 + 256 + lane * 4];
            o.x += q0 * (float)zv[0]; o.y += q1 * (float)zv[1];
            o.z += q2 * (float)zv[2]; o.w += q3 * (float)zv[3];
        }
    }
    for (int off = 1; off < 64; off <<= 1) {
        l0 += __shfl_xor(l0, off); l1 += __shfl_xor(l1, off);
        l2 += __shfl_xor(l2, off); l3 += __shfl_xor(l3, off);
    }
    if (cnt > 0) { o.x /= l0; o.y /= l1; o.z /= l2; o.w /= l3; }
    size_t ob = (size_t)n * 256;
    __builtin_nontemporal_store(o.x, &out[ob + lane]);
    __builtin_nontemporal_store(o.y, &out[ob + 64 + lane]);
    __builtin_nontemporal_store(o.z, &out[ob + 128 + lane]);
    __builtin_nontemporal_store(o.w, &out[ob + 192 + lane]);
}

extern "C" void kernel_launch(void* const* d_in, const int* in_sizes, int n_in,
                              void* d_out, int out_size, void* d_ws, size_t ws_size,
                              hipStream_t stream) {
    const float* hmat = (const float*)d_in[0];
    const float* W    = (const float*)d_in[1];
    const float* att  = (const float*)d_in[2];
    const int*   src  = (const int*)d_in[3];
    const int*   dst  = (const int*)d_in[4];
    int N = in_sizes[0] / D_IN;
    int E = in_sizes[3];
    float* out = (float*)d_out;

    // workspace layout (16B-aligned); identical to the proven r0/r6 layout, ~113.5 MB
    float* z_t      = (float*)d_ws;                       // N*256 fp32 (fp16 image in-row)
    float* es_ed    = z_t + (size_t)N * 256;              // N*8
    _Float16* Wt_hi = (_Float16*)(es_ed + (size_t)N * 8); // 65536 fp16
    _Float16* Wt_lo = Wt_hi + 65536;                      // 65536 fp16
    int*   counts   = (int*)(Wt_lo + 65536);              // N
    int*   cursor   = counts + N;                         // N (contiguous with counts)
    int*   row_start= cursor + N;                         // N
    int*   bsums    = row_start + N;                      // <=256
    int*   csr_src  = bsums + 256;                        // E

    int NB = (N + 1023) / 1024;

    hipMemsetAsync(counts, 0, (size_t)2 * N * sizeof(int), stream);
    wprep_kernel<<<256, 256, 0, stream>>>(W, Wt_hi, Wt_lo);
    gemm_kernel<<<((N + 127) / 128) * 2, 512, 0, stream>>>(hmat, Wt_hi, Wt_lo, z_t, N);
    esed_kernel<<<(N * 64 + 255) / 256, 256, 0, stream>>>(z_t, att, es_ed, N);
    hist_kernel<<<(E + 255) / 256, 256, 0, stream>>>(dst, counts, E);
    scanA_kernel<<<NB, 256, 0, stream>>>(counts, bsums, N);
    scanB_kernel<<<1, 256, 0, stream>>>(bsums, NB);
    scanC_kernel<<<NB, 256, 0, stream>>>(counts, bsums, row_start, N);
    scatter_kernel<<<(E + 255) / 256, 256, 0, stream>>>(src, dst, row_start, cursor, csr_src, E);
    aggregate_kernel<<<(N * 64 + 255) / 256, 256, 0, stream>>>((const _Float16*)z_t, es_ed, csr_src, row_start, counts, out, N);
}

// Round 10
// 513.319 us; speedup vs baseline: 1.2070x; 1.1025x over previous
//
#include <hip/hip_runtime.h>
#include <math.h>

#define NEGV (-1000.0f)
#define SLOPE 0.01f
#define D_IN 256
#define LDK 72

typedef _Float16 half8 __attribute__((ext_vector_type(8)));
typedef _Float16 half4h __attribute__((ext_vector_type(4)));
typedef float f32x4 __attribute__((ext_vector_type(4)));

__device__ __forceinline__ int rli(int v, int l) {
    return __builtin_amdgcn_readlane(v, l);
}
__device__ __forceinline__ void nt_store2(float* p, float a, float b) {
    float2 v = make_float2(a, b);
    __builtin_nontemporal_store(__builtin_bit_cast(double, v), (double*)p);
}

// ---------- W prep: W[h][k][f] fp32 -> split fp16 Wt_hi/Wt_lo[c][k], c=f*4+h ----------
__global__ void wprep_kernel(const float* __restrict__ W, _Float16* __restrict__ Wt_hi,
                             _Float16* __restrict__ Wt_lo) {
    int i = blockIdx.x * 256 + threadIdx.x;   // 65536, input-coalesced
    int f = i & 63;
    int k = (i >> 6) & 255;
    int h = i >> 14;
    float w = W[i];
    _Float16 hi = (_Float16)w;
    _Float16 lo = (_Float16)(w - (float)hi);
    int c = f * 4 + h;
    Wt_hi[c * 256 + k] = hi;
    Wt_lo[c * 256 + k] = lo;
}

// ---------- split-fp16 MFMA GEMM: z_t[n][c] = sum_k h[n][k]*Wt[c][k], fp32 out ----------
// (byte-identical to the proven r0 GEMM)
__global__ __launch_bounds__(512) void gemm_kernel(const float* __restrict__ hmat,
        const _Float16* __restrict__ Wt_hi, const _Float16* __restrict__ Wt_lo,
        float* __restrict__ z_t, int N) {
    __shared__ __align__(16) _Float16 smem[4 * 128 * LDK];   // 73728 B
    _Float16* A_hi = smem;
    _Float16* A_lo = smem + 128 * LDK;
    _Float16* B_hi = smem + 2 * 128 * LDK;
    _Float16* B_lo = smem + 3 * 128 * LDK;
    const int t = threadIdx.x;
    const int lane = t & 63;
    const int w = t >> 6;
    const int quad = lane >> 4;
    const int m16 = lane & 15;
    const int rg = w & 3;
    const int cg = w >> 2;
    const int n0 = (blockIdx.x >> 1) * 128;
    const int c0 = (blockIdx.x & 1) * 128;

    f32x4 acc[2][4];
#pragma unroll
    for (int rt = 0; rt < 2; rt++)
#pragma unroll
        for (int ct = 0; ct < 4; ct++) acc[rt][ct] = (f32x4){0.f, 0.f, 0.f, 0.f};

    for (int kc = 0; kc < 256; kc += 64) {
        __syncthreads();
        // stage A: 128 rows x 64 k, fp32 -> hi/lo fp16
#pragma unroll
        for (int i = 0; i < 4; i++) {
            int idx = i * 512 + t;                    // 0..2047
            int row = idx >> 4, q = idx & 15;
            int rr = min(n0 + row, N - 1);            // clamp; garbage rows masked at store
            float4 v = *(const float4*)&hmat[(size_t)rr * 256 + kc + q * 4];
            half4h hv, lv;
            hv[0] = (_Float16)v.x; lv[0] = (_Float16)(v.x - (float)hv[0]);
            hv[1] = (_Float16)v.y; lv[1] = (_Float16)(v.y - (float)hv[1]);
            hv[2] = (_Float16)v.z; lv[2] = (_Float16)(v.z - (float)hv[2]);
            hv[3] = (_Float16)v.w; lv[3] = (_Float16)(v.w - (float)hv[3]);
            *(half4h*)&A_hi[row * LDK + q * 4] = hv;
            *(half4h*)&A_lo[row * LDK + q * 4] = lv;
        }
        // stage B: 128 c x 64 k fp16 hi/lo
#pragma unroll
        for (int i = 0; i < 2; i++) {
            int idx = i * 512 + t;                    // 0..1023
            int c = idx >> 3, seg = idx & 7;
            float4 vh = *(const float4*)&Wt_hi[(c0 + c) * 256 + kc + seg * 8];
            float4 vl = *(const float4*)&Wt_lo[(c0 + c) * 256 + kc + seg * 8];
            *(float4*)&B_hi[c * LDK + seg * 8] = vh;
            *(float4*)&B_lo[c * LDK + seg * 8] = vl;
        }
        __syncthreads();
#pragma unroll
        for (int ks = 0; ks < 2; ks++) {
            half8 ah[2], al[2], bh[4], bl[4];
#pragma unroll
            for (int rt = 0; rt < 2; rt++) {
                int ro = ((rg * 2 + rt) * 16 + m16) * LDK + ks * 32 + quad * 8;
                ah[rt] = *(const half8*)&A_hi[ro];
                al[rt] = *(const half8*)&A_lo[ro];
            }
#pragma unroll
            for (int ct = 0; ct < 4; ct++) {
                int co = ((cg * 4 + ct) * 16 + m16) * LDK + ks * 32 + quad * 8;
                bh[ct] = *(const half8*)&B_hi[co];
                bl[ct] = *(const half8*)&B_lo[co];
            }
#pragma unroll
            for (int rt = 0; rt < 2; rt++)
#pragma unroll
                for (int ct = 0; ct < 4; ct++) {
                    acc[rt][ct] = __builtin_amdgcn_mfma_f32_16x16x32_f16(ah[rt], bh[ct], acc[rt][ct], 0, 0, 0);
                    acc[rt][ct] = __builtin_amdgcn_mfma_f32_16x16x32_f16(al[rt], bh[ct], acc[rt][ct], 0, 0, 0);
                    acc[rt][ct] = __builtin_amdgcn_mfma_f32_16x16x32_f16(ah[rt], bl[ct], acc[rt][ct], 0, 0, 0);
                }
        }
    }
    // epilogue: C/D col=lane&15, row=quad*4+reg; direct fp32 stores (16-lane coalesced)
#pragma unroll
    for (int rt = 0; rt < 2; rt++)
#pragma unroll
        for (int ct = 0; ct < 4; ct++)
#pragma unroll
            for (int r = 0; r < 4; r++) {
                int n = n0 + rg * 32 + rt * 16 + quad * 4 + r;
                int c = c0 + cg * 64 + ct * 16 + m16;
                if (n < N) z_t[(size_t)n * 256 + c] = acc[rt][ct][r];
            }
}

// ---------- es/ed per node (fp32 z) + in-row fp16 z image for the aggregation ----------
__global__ void esed_kernel(float* __restrict__ z_t, const float* __restrict__ att,
                            float* __restrict__ es_ed, int N) {
    int gid = blockIdx.x * blockDim.x + threadIdx.x;
    int n = gid >> 6;
    int lane = gid & 63;
    if (n >= N) return;
    float4 zv = *(const float4*)&z_t[(size_t)n * 256 + lane * 4];
    float ps0 = zv.x * att[0 * 128 + lane];
    float ps1 = zv.y * att[1 * 128 + lane];
    float ps2 = zv.z * att[2 * 128 + lane];
    float ps3 = zv.w * att[3 * 128 + lane];
    float pd0 = zv.x * att[0 * 128 + 64 + lane];
    float pd1 = zv.y * att[1 * 128 + 64 + lane];
    float pd2 = zv.z * att[2 * 128 + 64 + lane];
    float pd3 = zv.w * att[3 * 128 + 64 + lane];
    for (int off = 1; off < 64; off <<= 1) {
        ps0 += __shfl_xor(ps0, off); ps1 += __shfl_xor(ps1, off);
        ps2 += __shfl_xor(ps2, off); ps3 += __shfl_xor(ps3, off);
        pd0 += __shfl_xor(pd0, off); pd1 += __shfl_xor(pd1, off);
        pd2 += __shfl_xor(pd2, off); pd3 += __shfl_xor(pd3, off);
    }
    // fp16 image: half index n*512 + 256 + lane*4  (= byte n*1024 + 512 + lane*8)
    half4h h16;
    h16[0] = (_Float16)zv.x; h16[1] = (_Float16)zv.y;
    h16[2] = (_Float16)zv.z; h16[3] = (_Float16)zv.w;
    *(half4h*)((_Float16*)z_t + (size_t)n * 512 + 256 + lane * 4) = h16;
    if (lane == 0) {
        *(float4*)&es_ed[(size_t)n * 8]     = make_float4(ps0, ps1, ps2, ps3);
        *(float4*)&es_ed[(size_t)n * 8 + 4] = make_float4(pd0, pd1, pd2, pd3);
    }
}

// ---------- CSR build ----------
// hist also records each edge's within-bucket slot (the atomicAdd return), stored in the
// DEAD fp32 lower halves of z_t rows (bytes [0,512) of each row are unused after esed):
// slot i lives at int index (i>>7)*256 + (i&127). scatter then needs no atomics/cursor.
__global__ void hist_kernel(const int* __restrict__ dst, int* __restrict__ counts,
                            int* __restrict__ slot, int E) {
    int i = blockIdx.x * blockDim.x + threadIdx.x;
    if (i < E) {
        int sl = atomicAdd(&counts[dst[i]], 1);
        slot[((i >> 7) << 8) + (i & 127)] = sl;
    }
}

__global__ void scanA_kernel(const int* __restrict__ counts, int* __restrict__ bsums, int N) {
    __shared__ int lds[256];
    int t = threadIdx.x;
    int base = blockIdx.x * 1024 + t * 4;
    int s = 0;
    if (base + 3 < N) {
        int4 v = *(const int4*)&counts[base];
        s = v.x + v.y + v.z + v.w;
    } else {
        for (int u = 0; u < 4; u++) if (base + u < N) s += counts[base + u];
    }
    lds[t] = s; __syncthreads();
    for (int off = 128; off > 0; off >>= 1) {
        if (t < off) lds[t] += lds[t + off];
        __syncthreads();
    }
    if (t == 0) bsums[blockIdx.x] = lds[0];
}

__global__ void scanB_kernel(int* __restrict__ bsums, int nb) {
    __shared__ int lds[256];
    int t = threadIdx.x;
    int v = (t < nb) ? bsums[t] : 0;
    lds[t] = v; __syncthreads();
    for (int off = 1; off < 256; off <<= 1) {
        int x = (t >= off) ? lds[t - off] : 0;
        __syncthreads();
        lds[t] += x;
        __syncthreads();
    }
    if (t < nb) bsums[t] = lds[t] - v;   // exclusive
}

__global__ void scanC_kernel(const int* __restrict__ counts, const int* __restrict__ bsums,
                             int* __restrict__ row_start, int N) {
    __shared__ int lds[256];
    int t = threadIdx.x;
    int base = blockIdx.x * 1024 + t * 4;
    int4 v = make_int4(0, 0, 0, 0);
    if (base + 3 < N) v = *(const int4*)&counts[base];
    else {
        if (base + 0 < N) v.x = counts[base + 0];
        if (base + 1 < N) v.y = counts[base + 1];
        if (base + 2 < N) v.z = counts[base + 2];
    }
    int s = v.x + v.y + v.z + v.w;
    lds[t] = s; __syncthreads();
    for (int off = 1; off < 256; off <<= 1) {
        int x = (t >= off) ? lds[t - off] : 0;
        __syncthreads();
        lds[t] += x;
        __syncthreads();
    }
    int excl = lds[t] - s + bsums[blockIdx.x];
    int4 r;
    r.x = excl; r.y = r.x + v.x; r.z = r.y + v.y; r.w = r.z + v.z;
    if (base + 3 < N) *(int4*)&row_start[base] = r;
    else {
        if (base + 0 < N) row_start[base + 0] = r.x;
        if (base + 1 < N) row_start[base + 1] = r.y;
        if (base + 2 < N) row_start[base + 2] = r.z;
    }
}

__global__ void scatter_kernel(const int* __restrict__ src, const int* __restrict__ dst,
                               const int* __restrict__ row_start, const int* __restrict__ slot,
                               int* __restrict__ csr_src, int E) {
    int i = blockIdx.x * blockDim.x + threadIdx.x;
    if (i < E) {
        int d = dst[i];
        csr_src[row_start[d] + slot[((i >> 7) << 8) + (i & 127)]] = src[i];
    }
}

// ---------- aggregation: TWO nodes per wave (32 lanes each), online softmax ----------
// lane: half = lane>>5 selects node 2*wv+half; hl = lane&31 covers f-columns {2hl, 2hl+1}
// for all 4 heads (16 B of the node's fp16 z image per lane). Each z-row gather
// instruction serves two edges (one per half). Broadcasts use __shfl with a per-half
// uniform index (ds_bpermute; DS pipe is otherwise idle). Butterflies are 5 rounds.
__global__ __launch_bounds__(256) void aggregate_kernel(const _Float16* __restrict__ z16,
        const float* __restrict__ es_ed, const int* __restrict__ csr_src,
        const int* __restrict__ row_start, const int* __restrict__ counts,
        float* __restrict__ out, int N) {
    int gid = blockIdx.x * blockDim.x + threadIdx.x;
    int wv = gid >> 6;
    int lane = gid & 63;
    if (2 * wv >= N) return;              // wave-uniform
    int half = lane >> 5;
    int hl = lane & 31;
    int n = 2 * wv + half;
    int nn = min(n, N - 1);               // clamp for odd tails; store masked
    int cnt = counts[nn];
    int start = row_start[nn];
    float4 edn = *(const float4*)&es_ed[(size_t)nn * 8 + 4];
    int cmax = max(rli(cnt, 0), rli(cnt, 32));
    int hb = half << 5;

    float m0 = -INFINITY, m1 = -INFINITY, m2 = -INFINITY, m3 = -INFINITY;
    float l0 = 0.f, l1 = 0.f, l2 = 0.f, l3 = 0.f;
    float o0 = 0.f, o1 = 0.f, o2 = 0.f, o3 = 0.f;
    float o4 = 0.f, o5 = 0.f, o6 = 0.f, o7 = 0.f;

    for (int base = 0; base < cmax; base += 32) {
        int i = base + hl;
        int s = 0;
        float e0 = -INFINITY, e1 = -INFINITY, e2 = -INFINITY, e3 = -INFINITY;
        if (i < cnt) {
            s = csr_src[start + i];
            float4 esv = *(const float4*)&es_ed[(size_t)s * 8];
            float x0 = esv.x + edn.x; e0 = x0 > 0.f ? x0 : SLOPE * x0; if (e0 == 0.f) e0 = NEGV;
            float x1 = esv.y + edn.y; e1 = x1 > 0.f ? x1 : SLOPE * x1; if (e1 == 0.f) e1 = NEGV;
            float x2 = esv.z + edn.z; e2 = x2 > 0.f ? x2 : SLOPE * x2; if (e2 == 0.f) e2 = NEGV;
            float x3 = esv.w + edn.w; e3 = x3 > 0.f ? x3 : SLOPE * x3; if (e3 == 0.f) e3 = NEGV;
        }
        float c0 = e0, c1 = e1, c2 = e2, c3 = e3;
#pragma unroll
        for (int off = 1; off < 32; off <<= 1) {
            c0 = fmaxf(c0, __shfl_xor(c0, off)); c1 = fmaxf(c1, __shfl_xor(c1, off));
            c2 = fmaxf(c2, __shfl_xor(c2, off)); c3 = fmaxf(c3, __shfl_xor(c3, off));
        }
        float nm0 = fmaxf(m0, c0), nm1 = fmaxf(m1, c1), nm2 = fmaxf(m2, c2), nm3 = fmaxf(m3, c3);
        float sc0 = __expf(m0 - nm0), sc1 = __expf(m1 - nm1);
        float sc2 = __expf(m2 - nm2), sc3 = __expf(m3 - nm3);
        o0 *= sc0; o1 *= sc1; o2 *= sc2; o3 *= sc3;
        o4 *= sc0; o5 *= sc1; o6 *= sc2; o7 *= sc3;
        l0 *= sc0; l1 *= sc1; l2 *= sc2; l3 *= sc3;
        m0 = nm0; m1 = nm1; m2 = nm2; m3 = nm3;

        float p0 = 0.f, p1 = 0.f, p2 = 0.f, p3 = 0.f;
        if (i < cnt) {
            p0 = __expf(e0 - m0); p1 = __expf(e1 - m1);
            p2 = __expf(e2 - m2); p3 = __expf(e3 - m3);
        }
        l0 += p0; l1 += p1; l2 += p2; l3 += p3;

        int jmax = min(32, cmax - base);
        int j = 0;
        for (; j + 7 < jmax; j += 8) {
            half8 zz[8]; float4 qq[8];
#pragma unroll
            for (int u = 0; u < 8; u++) {
                int idx = hb + j + u;             // uniform within each half
                int ss = __shfl(s, idx);
                qq[u] = make_float4(__shfl(p0, idx), __shfl(p1, idx),
                                    __shfl(p2, idx), __shfl(p3, idx));
                zz[u] = *(const half8*)&z16[(size_t)ss * 512 + 256 + hl * 8];
            }
#pragma unroll
            for (int u = 0; u < 8; u++) {
                o0 += qq[u].x * (float)zz[u][0]; o1 += qq[u].y * (float)zz[u][1];
                o2 += qq[u].z * (float)zz[u][2]; o3 += qq[u].w * (float)zz[u][3];
                o4 += qq[u].x * (float)zz[u][4]; o5 += qq[u].y * (float)zz[u][5];
                o6 += qq[u].z * (float)zz[u][6]; o7 += qq[u].w * (float)zz[u][7];
            }
        }
        for (; j < jmax; ++j) {
            int idx = hb + j;
            int ss = __shfl(s, idx);
            float q0 = __shfl(p0, idx), q1 = __shfl(p1, idx);
            float q2 = __shfl(p2, idx), q3 = __shfl(p3, idx);
            half8 zv = *(const half8*)&z16[(size_t)ss * 512 + 256 + hl * 8];
            o0 += q0 * (float)zv[0]; o1 += q1 * (float)zv[1];
            o2 += q2 * (float)zv[2]; o3 += q3 * (float)zv[3];
            o4 += q0 * (float)zv[4]; o5 += q1 * (float)zv[5];
            o6 += q2 * (float)zv[6]; o7 += q3 * (float)zv[7];
        }
    }
#pragma unroll
    for (int off = 1; off < 32; off <<= 1) {
        l0 += __shfl_xor(l0, off); l1 += __shfl_xor(l1, off);
        l2 += __shfl_xor(l2, off); l3 += __shfl_xor(l3, off);
    }
    if (n < N) {
        if (cnt > 0) {
            o0 /= l0; o1 /= l1; o2 /= l2; o3 /= l3;
            o4 /= l0; o5 /= l1; o6 /= l2; o7 /= l3;
        }
        float* ob = &out[(size_t)n * 256 + 2 * hl];
        nt_store2(ob + 0,   o0, o4);
        nt_store2(ob + 64,  o1, o5);
        nt_store2(ob + 128, o2, o6);
        nt_store2(ob + 192, o3, o7);
    }
}

extern "C" void kernel_launch(void* const* d_in, const int* in_sizes, int n_in,
                              void* d_out, int out_size, void* d_ws, size_t ws_size,
                              hipStream_t stream) {
    const float* hmat = (const float*)d_in[0];
    const float* W    = (const float*)d_in[1];
    const float* att  = (const float*)d_in[2];
    const int*   src  = (const int*)d_in[3];
    const int*   dst  = (const int*)d_in[4];
    int N = in_sizes[0] / D_IN;
    int E = in_sizes[3];
    float* out = (float*)d_out;

    // workspace layout (16B-aligned); identical to the proven r0/r6 layout, ~113.5 MB
    float* z_t      = (float*)d_ws;                       // N*256 fp32 (fp16 image in-row;
                                                          // lower halves reused for slot[])
    float* es_ed    = z_t + (size_t)N * 256;              // N*8
    _Float16* Wt_hi = (_Float16*)(es_ed + (size_t)N * 8); // 65536 fp16
    _Float16* Wt_lo = Wt_hi + 65536;                      // 65536 fp16
    int*   counts   = (int*)(Wt_lo + 65536);              // N
    int*   cursor   = counts + N;                         // N (unused; layout kept)
    int*   row_start= cursor + N;                         // N
    int*   bsums    = row_start + N;                      // <=256
    int*   csr_src  = bsums + 256;                        // E
    int*   slot     = (int*)z_t;                          // strided into dead row halves

    int NB = (N + 1023) / 1024;
    int aggBlocks = ((N + 1) / 2 + 3) / 4;                // 2 nodes/wave, 4 waves/block

    hipMemsetAsync(counts, 0, (size_t)N * sizeof(int), stream);
    wprep_kernel<<<256, 256, 0, stream>>>(W, Wt_hi, Wt_lo);
    gemm_kernel<<<((N + 127) / 128) * 2, 512, 0, stream>>>(hmat, Wt_hi, Wt_lo, z_t, N);
    esed_kernel<<<(N * 64 + 255) / 256, 256, 0, stream>>>(z_t, att, es_ed, N);
    hist_kernel<<<(E + 255) / 256, 256, 0, stream>>>(dst, counts, slot, E);
    scanA_kernel<<<NB, 256, 0, stream>>>(counts, bsums, N);
    scanB_kernel<<<1, 256, 0, stream>>>(bsums, NB);
    scanC_kernel<<<NB, 256, 0, stream>>>(counts, bsums, row_start, N);
    scatter_kernel<<<(E + 255) / 256, 256, 0, stream>>>(src, dst, row_start, slot, csr_src, E);
    aggregate_kernel<<<aggBlocks, 256, 0, stream>>>((const _Float16*)z_t, es_ed, csr_src, row_start, counts, out, N);
}